// Round 8
// baseline (421.940 us; speedup 1.0000x reference)
//
#include <hip/hip_runtime.h>
#include <math.h>

#define PP 1000
#define NN 1000

typedef short bf16x8 __attribute__((ext_vector_type(8)));
typedef float f32x16 __attribute__((ext_vector_type(16)));
typedef unsigned u32x4 __attribute__((ext_vector_type(4)));

static __device__ __forceinline__ int imin(int a, int b) { return a < b ? a : b; }

static __device__ __forceinline__ ushort f2bf(float f) {
  unsigned u = __builtin_bit_cast(unsigned, f);
  u = (u + 0x7FFFu + ((u >> 16) & 1u)) >> 16;
  return (ushort)u;
}
static __device__ __forceinline__ unsigned cvt_pk_bf16(float lo, float hi) {
  unsigned r;
  asm("v_cvt_pk_bf16_f32 %0, %1, %2" : "=v"(r) : "v"(lo), "v"(hi));
  return r;
}

// D row index for mfma_32x32x16 reg j (half = lane>>5)
#define ROWF(j, half) (((j) & 3) + 8 * ((j) >> 2) + 4 * (half))

// ---------------------------------------------------------------------------
// f32 [16*1000][256] -> bf16 padded [16*1024][256]
// ---------------------------------------------------------------------------
__global__ __launch_bounds__(256) void conv_pad(const float* __restrict__ src,
                                                ushort* __restrict__ dst) {
  const int i = blockIdx.x * 256 + threadIdx.x;
  const int row = i >> 5;
  const int c8 = (i & 31) * 8;
  const int b = row / 1000;
  const int p = row - b * 1000;
  const float4 a0 = *(const float4*)&src[(size_t)row * 256 + c8];
  const float4 a1 = *(const float4*)&src[(size_t)row * 256 + c8 + 4];
  ushort4 o0, o1;
  o0.x = f2bf(a0.x); o0.y = f2bf(a0.y); o0.z = f2bf(a0.z); o0.w = f2bf(a0.w);
  o1.x = f2bf(a1.x); o1.y = f2bf(a1.y); o1.z = f2bf(a1.z); o1.w = f2bf(a1.w);
  ushort* d = &dst[((size_t)(b * 1024 + p)) * 256 + c8];
  *(ushort4*)d = o0;
  *(ushort4*)(d + 4) = o1;
}

// ---------------------------------------------------------------------------
// Weight transpose+convert: W f32 [256 k][256 c] -> Wt bf16 [256 c][256 k]
// ---------------------------------------------------------------------------
__global__ __launch_bounds__(256) void conv_w(
    const float* __restrict__ w0, const float* __restrict__ w1,
    const float* __restrict__ w2, const float* __restrict__ w3,
    ushort* __restrict__ t0, ushort* __restrict__ t1,
    ushort* __restrict__ t2, ushort* __restrict__ t3) {
  const float* srcs[4] = {w0, w1, w2, w3};
  ushort* dsts[4] = {t0, t1, t2, t3};
  const float* W = srcs[blockIdx.y];
  ushort* T = dsts[blockIdx.y];
  __shared__ float L[64][65];
  const int t = threadIdx.x;
  const int k0 = (blockIdx.x & 3) * 64, c0 = (blockIdx.x >> 2) * 64;
#pragma unroll
  for (int i = 0; i < 4; ++i) {
    const int kr = (t >> 4) + i * 16;
    const int cq = (t & 15) * 4;
    const float4 v = *(const float4*)&W[(size_t)(k0 + kr) * 256 + c0 + cq];
    L[kr][cq + 0] = v.x; L[kr][cq + 1] = v.y;
    L[kr][cq + 2] = v.z; L[kr][cq + 3] = v.w;
  }
  __syncthreads();
#pragma unroll
  for (int i = 0; i < 4; ++i) {
    const int cl = (t >> 4) + i * 16;
    const int kq = (t & 15) * 4;
    ushort4 o;
    o.x = f2bf(L[kq + 0][cl]); o.y = f2bf(L[kq + 1][cl]);
    o.z = f2bf(L[kq + 2][cl]); o.w = f2bf(L[kq + 3][cl]);
    *(ushort4*)&T[(size_t)(c0 + cl) * 256 + k0 + kq] = o;
  }
}

// ---------------------------------------------------------------------------
// MFMA projection: C[p][c] = sum_k A[p][k] * Wt[c][k]   (A bf16 padded rows)
// MODE 0: flat bf16 padded out (K)   MODE 1: + attr rank-1 (Q)
// MODE 2: + bias (mh)                MODE 3: rows=n, out vt (V)
// ---------------------------------------------------------------------------
template <int MODE>
__global__ __launch_bounds__(256) void proj_mfma(
    const ushort* __restrict__ A, const ushort* __restrict__ Wt,
    ushort* __restrict__ out, const float* __restrict__ ex1,
    const float* __restrict__ ex2) {
  const int t = threadIdx.x;
  const int w = t >> 6, l = t & 63;
  const int lp = l & 31, half = l >> 5;
  const int b = blockIdx.z;
  const int c0 = blockIdx.x * 64 + (w & 1) * 32;
  const int p0 = blockIdx.y * 64 + (w >> 1) * 32;
  const ushort* arow =
      &A[((size_t)(b * 1024 + imin(p0 + lp, PP - 1))) * 256 + half * 8];
  const ushort* brow = &Wt[(size_t)(c0 + lp) * 256 + half * 8];
  f32x16 acc;
#pragma unroll
  for (int j = 0; j < 16; ++j) acc[j] = 0.f;
#pragma unroll
  for (int kt = 0; kt < 16; ++kt) {
    const bf16x8 af = *(const bf16x8*)&arow[kt * 16];
    const bf16x8 bf = *(const bf16x8*)&brow[kt * 16];
    acc = __builtin_amdgcn_mfma_f32_32x32x16_bf16(af, bf, acc, 0, 0, 0);
  }
  const int c = c0 + lp;
  if (MODE == 1) {
    const float wq = ex2[c];
#pragma unroll
    for (int j = 0; j < 16; ++j) {
      const int p = p0 + ROWF(j, half);
      acc[j] += ex1[b * 1000 + imin(p, PP - 1)] * wq;
    }
  }
  if (MODE == 2) {
    const float bias = ex2[c];
#pragma unroll
    for (int j = 0; j < 16; ++j) acc[j] += bias;
  }
  if (MODE == 3) {  // rows=n, write transposed into vt
    const int h = c >> 4, d = c & 15;
    ushort* vr = &out[((size_t)((b * 16 + h) * 16 + d)) * 1024];
#pragma unroll
    for (int q = 0; q < 4; ++q) {
      ushort4 o;
      o.x = f2bf(acc[4 * q + 0]); o.y = f2bf(acc[4 * q + 1]);
      o.z = f2bf(acc[4 * q + 2]); o.w = f2bf(acc[4 * q + 3]);
      *(ushort4*)&vr[p0 + 8 * q + 4 * half] = o;
    }
  } else {
#pragma unroll
    for (int j = 0; j < 16; ++j) {
      const int p = p0 + ROWF(j, half);
      out[((size_t)(b * 1024 + p)) * 256 + c] = f2bf(acc[j]);
    }
  }
}

// ---------------------------------------------------------------------------
// Swapped-QK^T MFMA attention, n-SPLIT across blockIdx.y (nh = 0/1), each
// block covers nt in [16*nh, 16*nh+16). Fixed-base softmax e = exp(s-8)
// (verified round 5) -> halves combine by plain addition in attn_combine.
// Body otherwise identical to round-7 attn_mfma2 (verified).
// Grid (32, 2, 16) x 512 thr = 8192 waves (100% capacity).
// Partials: pacc[nh][b][h][1024 p][16 d] f32, pl[nh][b][h][1024 p] f32.
// ---------------------------------------------------------------------------
__global__ __launch_bounds__(512) void attn_split(
    const ushort* __restrict__ qb, const ushort* __restrict__ kb,
    const ushort* __restrict__ vt, const float* __restrict__ mask,
    float* __restrict__ pacc, float* __restrict__ pl) {
  const int t = threadIdx.x;
  const int l = t & 63;
  const int w = t >> 6;      // wave 0..7
  const int lp = l & 31;
  const int half = l >> 5;
  const int b = blockIdx.z;
  const int nh = blockIdx.y;  // n-half
  const int p0 = blockIdx.x * 32;
  const int h0 = w * 2;

  const int pm = imin(p0 + lp, PP - 1);
  const float* mrow = &mask[((size_t)b * PP + pm) * NN];

  bf16x8 qf[2];
#pragma unroll
  for (int hh = 0; hh < 2; ++hh)
    qf[hh] = *(const bf16x8*)&qb[((size_t)(b * 1024 + p0 + lp)) * 256 +
                                 (h0 + hh) * 16 + half * 8];

  f32x16 acc[2];
  float l_[2] = {0.f, 0.f};
#pragma unroll
  for (int hh = 0; hh < 2; ++hh)
#pragma unroll
    for (int j = 0; j < 16; ++j) acc[hh][j] = 0.f;

  for (int nt = nh * 16; nt < nh * 16 + 16; ++nt) {
    const int n0 = nt * 32;
    float mqa[16];
    if (nt < 31) {
#pragma unroll
      for (int q = 0; q < 4; ++q) {
        const float4 v = *(const float4*)&mrow[n0 + q * 8 + half * 4];
        mqa[q * 4 + 0] = v.x; mqa[q * 4 + 1] = v.y;
        mqa[q * 4 + 2] = v.z; mqa[q * 4 + 3] = v.w;
      }
    } else {
#pragma unroll
      for (int j = 0; j < 16; ++j) {
        const int nj = n0 + ROWF(j, half);
        mqa[j] = mrow[imin(nj, NN - 1)];
      }
    }
#pragma unroll
    for (int hh = 0; hh < 2; ++hh) {
      const int h = h0 + hh;
      const bf16x8 kf =
          *(const bf16x8*)&kb[((size_t)(b * 1024 + n0 + lp)) * 256 + h * 16 +
                              half * 8];
      f32x16 cc;
#pragma unroll
      for (int j = 0; j < 16; ++j) cc[j] = 0.f;
      cc = __builtin_amdgcn_mfma_f32_32x32x16_bf16(kf, qf[hh], cc, 0, 0, 0);
      float e[16];
#pragma unroll
      for (int j = 0; j < 16; ++j) {
        float s = fmaf(cc[j], 0.25f, mqa[j]);
        if (nt == 31) {
          const int nj = n0 + ROWF(j, half);
          if (nj >= NN) s = -1e30f;
        }
        e[j] = __expf(s - 8.0f);  // fixed-base: exact, verified round 5
        l_[hh] += e[j];
      }
      // pack P to bf16 A-frags (k = n_local). Half-exchange via shfl_xor(32).
      unsigned pk0 = cvt_pk_bf16(e[0], e[1]),   pk1 = cvt_pk_bf16(e[2], e[3]);
      unsigned pk2 = cvt_pk_bf16(e[4], e[5]),   pk3 = cvt_pk_bf16(e[6], e[7]);
      unsigned pk4 = cvt_pk_bf16(e[8], e[9]),   pk5 = cvt_pk_bf16(e[10], e[11]);
      unsigned pk6 = cvt_pk_bf16(e[12], e[13]), pk7 = cvt_pk_bf16(e[14], e[15]);
      const unsigned s0 = (unsigned)__shfl_xor((int)pk0, 32, 64);
      const unsigned s2 = (unsigned)__shfl_xor((int)pk2, 32, 64);
      const unsigned s1 = (unsigned)__shfl_xor((int)pk1, 32, 64);
      const unsigned s3 = (unsigned)__shfl_xor((int)pk3, 32, 64);
      const unsigned s4 = (unsigned)__shfl_xor((int)pk4, 32, 64);
      const unsigned s6 = (unsigned)__shfl_xor((int)pk6, 32, 64);
      const unsigned s5 = (unsigned)__shfl_xor((int)pk5, 32, 64);
      const unsigned s7 = (unsigned)__shfl_xor((int)pk7, 32, 64);
      u32x4 w1, w2;
      w1[0] = half ? s2 : pk0;
      w1[1] = half ? s3 : pk1;
      w1[2] = half ? pk2 : s0;
      w1[3] = half ? pk3 : s1;
      w2[0] = half ? s6 : pk4;
      w2[1] = half ? s7 : pk5;
      w2[2] = half ? pk6 : s4;
      w2[3] = half ? pk7 : s5;
      const bf16x8 pf1 = __builtin_bit_cast(bf16x8, w1);
      const bf16x8 pf2 = __builtin_bit_cast(bf16x8, w2);
      const ushort* vrow =
          &vt[((size_t)((b * 16 + h) * 16 + (lp & 15))) * 1024];
      const bf16x8 vf1 = *(const bf16x8*)&vrow[n0 + half * 8];
      const bf16x8 vf2 = *(const bf16x8*)&vrow[n0 + 16 + half * 8];
      acc[hh] = __builtin_amdgcn_mfma_f32_32x32x16_bf16(pf1, vf1, acc[hh], 0, 0, 0);
      acc[hh] = __builtin_amdgcn_mfma_f32_32x32x16_bf16(pf2, vf2, acc[hh], 0, 0, 0);
    }
  }
  // epilogue: store raw partials (no normalization)
#pragma unroll
  for (int hh = 0; hh < 2; ++hh) {
    l_[hh] += __shfl_xor(l_[hh], 32, 64);  // merge halves once at end
    const size_t slab = ((size_t)((nh * 16 + b) * 16 + h0 + hh)) * 1024;
    if (l < 32) pl[slab + p0 + lp] = l_[hh];
#pragma unroll
    for (int j = 0; j < 16; ++j) {
      const int pj = ROWF(j, half);
      if (lp < 16) pacc[(slab + p0 + pj) * 16 + lp] = acc[hh][j];
    }
  }
}

// ---------------------------------------------------------------------------
// Combine the two n-half partials: aob = bf16((a0+a1)/(l0+l1)), padded layout.
// One thread per (b,h,p,d-quad). Pad rows p>=1000 skipped (never read later).
// ---------------------------------------------------------------------------
__global__ __launch_bounds__(256) void attn_combine(
    const float* __restrict__ pacc, const float* __restrict__ pl,
    ushort* __restrict__ aob) {
  const int i = blockIdx.x * 256 + threadIdx.x;  // 1,048,576 total
  const int dq = i & 3;
  const int r = i >> 2;        // bh*1024 + p
  const int p = r & 1023;
  if (p >= PP) return;
  const int bh = r >> 10;      // b*16 + h
  const float l0 = pl[(size_t)bh * 1024 + p];
  const float l1 = pl[(size_t)(256 + bh) * 1024 + p];
  const float inv = 1.0f / (l0 + l1);
  const float4 a0 = *(const float4*)&pacc[((size_t)bh * 1024 + p) * 16 + dq * 4];
  const float4 a1 =
      *(const float4*)&pacc[((size_t)(256 + bh) * 1024 + p) * 16 + dq * 4];
  ushort4 o;
  o.x = f2bf((a0.x + a1.x) * inv);
  o.y = f2bf((a0.y + a1.y) * inv);
  o.z = f2bf((a0.z + a1.z) * inv);
  o.w = f2bf((a0.w + a1.w) * inv);
  const int b = bh >> 4, h = bh & 15;
  *(ushort4*)&aob[((size_t)(b * 1024 + p)) * 256 + h * 16 + dq * 4] = o;
}

// ---------------------------------------------------------------------------
// Fused score2 + clip-tanh + mask + row-softmax (verified round 7).
// ---------------------------------------------------------------------------
__global__ __launch_bounds__(512, 1) void fused_probe(
    const ushort* __restrict__ ndb, const ushort* __restrict__ mbb,
    const float* __restrict__ mask, float* __restrict__ out) {
  __shared__ float smax[8][32];
  __shared__ float ssum[8][32];
  const int t = threadIdx.x;
  const int l = t & 63, w = t >> 6;
  const int lp = l & 31, half = l >> 5;
  const int b = blockIdx.y;
  const int p0 = blockIdx.x * 32;

  const ushort* brow = &mbb[((size_t)(b * 1024 + p0 + lp)) * 256 + half * 8];
  f32x16 acc[4];
#pragma unroll
  for (int tt = 0; tt < 4; ++tt)
#pragma unroll
    for (int j = 0; j < 16; ++j) acc[tt][j] = 0.f;

#pragma unroll
  for (int tt = 0; tt < 4; ++tt) {
    const int n = imin(w * 128 + tt * 32 + lp, NN - 1);
    const ushort* arow = &ndb[((size_t)(b * 1024 + n)) * 256 + half * 8];
#pragma unroll
    for (int kt = 0; kt < 16; ++kt) {
      const bf16x8 af = *(const bf16x8*)&arow[kt * 16];
      const bf16x8 bf = *(const bf16x8*)&brow[kt * 16];
      acc[tt] = __builtin_amdgcn_mfma_f32_32x32x16_bf16(af, bf, acc[tt], 0, 0, 0);
    }
  }
  const float* mrow2 = &mask[((size_t)b * PP + imin(p0 + lp, PP - 1)) * NN];
  float vmax = -1e30f;
#pragma unroll
  for (int tt = 0; tt < 4; ++tt) {
#pragma unroll
    for (int q = 0; q < 4; ++q) {
      const int nb = w * 128 + tt * 32 + 8 * q + 4 * half;
      float4 mv = make_float4(0.f, 0.f, 0.f, 0.f);
      if (nb < NN) mv = *(const float4*)&mrow2[nb];
#pragma unroll
      for (int r = 0; r < 4; ++r) {
        const int j = 4 * q + r;
        const float E = __expf(acc[tt][j] * 0.125f);
        float v = 10.0f - 20.0f / (E + 1.0f);
        v += (r == 0 ? mv.x : r == 1 ? mv.y : r == 2 ? mv.z : mv.w);
        if (nb + r >= NN) v = -1e30f;
        acc[tt][j] = v;
        vmax = fmaxf(vmax, v);
      }
    }
  }
  vmax = fmaxf(vmax, __shfl_xor(vmax, 32, 64));
  if (half == 0) smax[w][lp] = vmax;
  __syncthreads();
  float mg = smax[0][lp];
#pragma unroll
  for (int ww = 1; ww < 8; ++ww) mg = fmaxf(mg, smax[ww][lp]);
  float lsum = 0.f;
#pragma unroll
  for (int tt = 0; tt < 4; ++tt)
#pragma unroll
    for (int j = 0; j < 16; ++j) {
      const float e = __expf(acc[tt][j] - mg);
      acc[tt][j] = e;
      lsum += e;
    }
  lsum += __shfl_xor(lsum, 32, 64);
  if (half == 0) ssum[w][lp] = lsum;
  __syncthreads();
  float lt = 0.f;
#pragma unroll
  for (int ww = 0; ww < 8; ++ww) lt += ssum[ww][lp];
  const float inv = 1.0f / lt;
  const int p = p0 + lp;
  if (p < PP) {
    float* orow = &out[((size_t)b * PP + p) * NN];
#pragma unroll
    for (int tt = 0; tt < 4; ++tt)
#pragma unroll
      for (int q = 0; q < 4; ++q) {
        const int nb = w * 128 + tt * 32 + 8 * q + 4 * half;
        if (nb < NN)
          *(float4*)&orow[nb] =
              make_float4(acc[tt][4 * q + 0] * inv, acc[tt][4 * q + 1] * inv,
                          acc[tt][4 * q + 2] * inv, acc[tt][4 * q + 3] * inv);
      }
  }
}

// ---------------------------------------------------------------------------
extern "C" void kernel_launch(void* const* d_in, const int* in_sizes, int n_in,
                              void* d_out, int out_size, void* d_ws,
                              size_t ws_size, hipStream_t stream) {
  const float* last  = (const float*)d_in[0];
  const float* attr  = (const float*)d_in[1];
  const float* mask  = (const float*)d_in[2];
  const float* nodes = (const float*)d_in[3];
  const float* Wq    = (const float*)d_in[4];
  const float* Wk    = (const float*)d_in[5];
  const float* Wv    = (const float*)d_in[6];
  const float* Wc    = (const float*)d_in[7];
  const float* bc    = (const float*)d_in[8];
  float* out = (float*)d_out;

  char* base = (char*)d_ws;
  ushort* ndb  = (ushort*)(base);               //  8,388,608
  ushort* ldb  = (ushort*)(base + 8388608);     //  8,388,608
  ushort* kbb  = (ushort*)(base + 16777216);    //  8,388,608
  ushort* qbb  = (ushort*)(base + 25165824);    //  8,388,608
  ushort* vtb  = (ushort*)(base + 33554432);    //  8,388,608
  ushort* aob  = (ushort*)(base + 41943040);    //  8,388,608
  ushort* mbb  = (ushort*)(base + 50331648);    //  8,388,608
  ushort* wkt  = (ushort*)(base + 58720256);    //    131,072
  ushort* wvt  = (ushort*)(base + 58851328);    //    131,072
  ushort* wqt  = (ushort*)(base + 58982400);    //    131,072
  ushort* wct  = (ushort*)(base + 59113472);    //    131,072
  float*  pacc = (float*)(base + 59244544);     // 33,554,432
  float*  pl   = (float*)(base + 92798976);     //  2,097,152  (~94.9 MB)

  const dim3 blk(256);
  conv_w<<<dim3(16, 4), blk, 0, stream>>>(Wk, Wv, Wq, Wc, wkt, wvt, wqt, wct);
  conv_pad<<<dim3(2000), blk, 0, stream>>>(nodes, ndb);
  conv_pad<<<dim3(2000), blk, 0, stream>>>(last, ldb);
  proj_mfma<0><<<dim3(4, 16, 16), blk, 0, stream>>>(ndb, wkt, kbb, nullptr, nullptr);
  proj_mfma<1><<<dim3(4, 16, 16), blk, 0, stream>>>(ldb, wqt, qbb, attr, Wq + 256 * 256);
  proj_mfma<3><<<dim3(4, 16, 16), blk, 0, stream>>>(ndb, wvt, vtb, nullptr, nullptr);
  attn_split<<<dim3(32, 2, 16), dim3(512), 0, stream>>>(qbb, kbb, vtb, mask, pacc, pl);
  attn_combine<<<dim3(4096), blk, 0, stream>>>(pacc, pl, aob);
  proj_mfma<2><<<dim3(4, 16, 16), blk, 0, stream>>>(aob, wct, mbb, nullptr, bc);
  fused_probe<<<dim3(32, 16), dim3(512), 0, stream>>>(ndb, mbb, mask, out);
}